// Round 1
// 513.305 us; speedup vs baseline: 1.0349x; 1.0349x over previous
//
#include <hip/hip_runtime.h>

#define NN 2304
#define CC 192
#define NBATCH 16

typedef unsigned short u16;
typedef __bf16 bf16x8 __attribute__((ext_vector_type(8)));
typedef float f32x4 __attribute__((ext_vector_type(4)));
typedef float f32x16 __attribute__((ext_vector_type(16)));

__device__ __forceinline__ u16 bf16bits(float f) {
  union { float f; unsigned u; } v;
  v.f = f;
  unsigned r = v.u + 0x7FFFu + ((v.u >> 16) & 1u);
  return (u16)(r >> 16);
}

// XOR-swizzled LDS element index for a [rows][192] bf16 tile (row stride 192).
// 8-element chunks are permuted within 8-chunk groups by row&7 (involution).
__device__ __forceinline__ int swzK(int row, int col) {
  int ch = col >> 3;
  int phys = (ch & ~7) | ((ch ^ row) & 7);
  return row * 192 + (phys << 3) + (col & 7);
}
// Same for [rows][64] bf16 tiles (8 chunks per row).
__device__ __forceinline__ int swz64(int row, int col) {
  int ch = (col >> 3) ^ row;
  return (row << 6) | ((ch & 7) << 3) | (col & 7);
}

// direct global->LDS 16B DMA; dest = wave-uniform base + lane*16
__device__ __forceinline__ void gll16(const u16* g, u16* l) {
  __builtin_amdgcn_global_load_lds(
      (const __attribute__((address_space(1))) u16*)g,
      (__attribute__((address_space(3))) u16*)l, 16, 0, 0);
}

// ---------------------------------------------------------------------------
// Kernel 1: LayerNorm over C, x[b,c,n] (fp32) -> xn[(b*N+n), c] (bf16)
// ---------------------------------------------------------------------------
__global__ __launch_bounds__(256) void ln_kernel(
    const float* __restrict__ x, const float* __restrict__ lnw,
    const float* __restrict__ lnb, u16* __restrict__ xn) {
  __shared__ float xt[192 * 65];
  __shared__ float psum[4][64], psq[4][64];
  __shared__ float mu_s[64], rs_s[64];
  __shared__ float lw_s[192], lb_s[192];
  int t = threadIdx.x;
  int b = blockIdx.y, n0 = blockIdx.x * 64;
  const float* xb = x + (size_t)b * CC * NN;
  if (t < 192) { lw_s[t] = lnw[t]; lb_s[t] = lnb[t]; }
#pragma unroll
  for (int i = 0; i < 48; ++i) {
    int idx = i * 256 + t;
    int c = idx >> 6, n = idx & 63;
    xt[c * 65 + n] = xb[(size_t)c * NN + n0 + n];
  }
  __syncthreads();
  {
    int n = t & 63, part = t >> 6;
    float s = 0.f, s2 = 0.f;
#pragma unroll
    for (int c = part * 48; c < part * 48 + 48; ++c) {
      float v = xt[c * 65 + n];
      s += v; s2 += v * v;
    }
    psum[part][n] = s; psq[part][n] = s2;
  }
  __syncthreads();
  if (t < 64) {
    float s = psum[0][t] + psum[1][t] + psum[2][t] + psum[3][t];
    float s2 = psq[0][t] + psq[1][t] + psq[2][t] + psq[3][t];
    float mu = s * (1.0f / 192.0f);
    float var = s2 * (1.0f / 192.0f) - mu * mu;
    mu_s[t] = mu;
    rs_s[t] = rsqrtf(var + 1e-5f);
  }
  __syncthreads();
#pragma unroll
  for (int i = 0; i < 12; ++i) {
    int u = i * 256 + t;
    int n = u / 48, cq = (u % 48) * 4;
    float mu = mu_s[n], rs = rs_s[n];
    alignas(8) u16 tmp[4];
#pragma unroll
    for (int k2 = 0; k2 < 4; ++k2) {
      float v = (xt[(cq + k2) * 65 + n] - mu) * rs * lw_s[cq + k2] + lb_s[cq + k2];
      tmp[k2] = bf16bits(v);
    }
    *(uint2*)&xn[((size_t)(b * NN + n0 + n)) * CC + cq] = *(uint2*)tmp;
  }
}

// ---------------------------------------------------------------------------
// Kernel 2: QKV projections. y = xn @ W^T. 64x64 tiles, K=192.
// z==2 (V) writes transposed: vt[b][d][n].
// ---------------------------------------------------------------------------
__global__ __launch_bounds__(256, 3) void qkv_gemm(
    const u16* __restrict__ xn, const float* __restrict__ Wq,
    const float* __restrict__ Wk, const float* __restrict__ Wv,
    u16* __restrict__ qb, u16* __restrict__ kb, u16* __restrict__ vtb) {
  __shared__ u16 xs[12288];
  __shared__ u16 wsm[12288];
  int t = threadIdx.x, w = t >> 6, lane = t & 63, l15 = lane & 15, qd = lane >> 4;
  int m0 = blockIdx.x * 64, n0 = blockIdx.y * 64, z = blockIdx.z;
  const float* W = (z == 0) ? Wq : (z == 1 ? Wk : Wv);
#pragma unroll
  for (int i = 0; i < 6; ++i) {
    int ch = i * 256 + t;
    int row = ch / 24, cin = (ch % 24) * 8;
    *(uint4*)&xs[swzK(row, cin)] = *(const uint4*)&xn[(size_t)(m0 + row) * 192 + cin];
  }
#pragma unroll
  for (int i = 0; i < 6; ++i) {
    int ch = i * 256 + t;
    int row = ch / 24, cin = (ch % 24) * 8;
    const float* src = &W[(size_t)(n0 + row) * 192 + cin];
    alignas(16) u16 tmp[8];
#pragma unroll
    for (int j = 0; j < 8; ++j) tmp[j] = bf16bits(src[j]);
    *(uint4*)&wsm[swzK(row, cin)] = *(uint4*)tmp;
  }
  __syncthreads();
  bf16x8 a[6];
#pragma unroll
  for (int kk = 0; kk < 6; ++kk)
    a[kk] = *(const bf16x8*)&xs[swzK(w * 16 + l15, kk * 32 + qd * 8)];
  const f32x4 fz = {0.f, 0.f, 0.f, 0.f};
  f32x4 acc[4];
#pragma unroll
  for (int ct = 0; ct < 4; ++ct) {
    acc[ct] = fz;
#pragma unroll
    for (int kk = 0; kk < 6; ++kk) {
      bf16x8 bfr = *(const bf16x8*)&wsm[swzK(ct * 16 + l15, kk * 32 + qd * 8)];
      acc[ct] = __builtin_amdgcn_mfma_f32_16x16x32_bf16(a[kk], bfr, acc[ct], 0, 0, 0);
    }
  }
  if (z < 2) {
    u16* outp = (z == 0) ? qb : kb;
#pragma unroll
    for (int ct = 0; ct < 4; ++ct)
#pragma unroll
      for (int r = 0; r < 4; ++r) {
        int m = m0 + w * 16 + qd * 4 + r;
        outp[(size_t)m * 192 + n0 + ct * 16 + l15] = bf16bits(acc[ct][r]);
      }
  } else {
    __syncthreads();
#pragma unroll
    for (int ct = 0; ct < 4; ++ct)
#pragma unroll
      for (int r = 0; r < 4; ++r)
        xs[swz64(ct * 16 + l15, w * 16 + qd * 4 + r)] = bf16bits(acc[ct][r]);
    __syncthreads();
    int b = blockIdx.x / 36, nb = (blockIdx.x % 36) * 64;
#pragma unroll
    for (int i = 0; i < 16; ++i) {
      int idx = i * 256 + t;
      int d = idx >> 6, nn = idx & 63;
      vtb[(size_t)b * 192 * NN + (size_t)(n0 + d) * NN + nb + nn] = xs[swz64(d, nn)];
    }
  }
}

// ---------------------------------------------------------------------------
// Kernel 3: fused flash-style attention, 32x32x16 MFMA, gll staging,
// packed P (lo=exp, hi=relu^2), counted-vmcnt 3-barrier pipeline.
// Wave w: qh=w>>1 (Q 32-row half), ch=w&1 (S K-col half == PV d-group).
// ---------------------------------------------------------------------------
__global__ __launch_bounds__(256, 2) void attn_kernel(
    const u16* __restrict__ qb, const u16* __restrict__ kb,
    const u16* __restrict__ vtb, const float* __restrict__ w1p,
    const float* __restrict__ w2p, const float* __restrict__ x,
    float* __restrict__ out) {
  __shared__ u16 sm[32768];                 // 64 KB exactly
  u16* klds = sm;                           // [64][192] bf16, swzK layout (24KB)
  u16* vlds = sm + 12288;                   // [192][64] bf16 V^T, swz64 (24KB)
  uint32_t* pu = (uint32_t*)(sm + 24576);   // [64 q][64 k] packed u32, chunk-swz (16KB)
  float* lbuf = (float*)(sm + 24576);       // epilogue overlay [64][2]
  float* olds = (float*)sm;                 // epilogue overlay [192][64]

  int t = threadIdx.x, w = t >> 6, lane = t & 63;
  int l31 = lane & 31, hi = lane >> 5;
  int qh = w >> 1, ch = w & 1;
  int bid = blockIdx.x;
  int qt = bid >> 4;                               // 0..35
  int b = ((bid & 7) << 1) | ((bid >> 3) & 1);     // 2 batches per XCD

  const u16* Qg = qb + ((size_t)b * NN + qt * 64) * CC;
  const u16* Kg = kb + (size_t)b * NN * CC;
  const u16* Vg = vtb + (size_t)b * CC * NN;

  // ---- stage Q into klds via gll (inverse-swizzled global source) ----
#pragma unroll
  for (int i = 0; i < 6; ++i) {
    int cid = i * 4 + w, sc = cid * 64 + lane;
    int row = sc / 24, pc = sc % 24;
    int gc = (pc & ~7) | ((pc ^ row) & 7);
    gll16(Qg + row * CC + gc * 8, &klds[cid * 512]);
  }
  asm volatile("s_waitcnt vmcnt(0)" ::: "memory");
  __syncthreads();
  bf16x8 qf[12];
#pragma unroll
  for (int ks = 0; ks < 12; ++ks)
    qf[ks] = *(const bf16x8*)&klds[swzK(qh * 32 + l31, ks * 16 + hi * 8)];
  asm volatile("s_waitcnt lgkmcnt(0)\ns_barrier" ::: "memory");

  // issue K tile 0 (overlaps nothing yet, but primes the pipeline)
#pragma unroll
  for (int i = 0; i < 6; ++i) {
    int cid = i * 4 + w, sc = cid * 64 + lane;
    int row = sc / 24, pc = sc % 24;
    int gc = (pc & ~7) | ((pc ^ row) & 7);
    gll16(Kg + (size_t)row * CC + gc * 8, &klds[cid * 512]);
  }

  f32x16 z16;
#pragma unroll
  for (int j = 0; j < 16; ++j) z16[j] = 0.f;
  f32x16 os[3], orl[3];
#pragma unroll
  for (int j = 0; j < 3; ++j) { os[j] = z16; orl[j] = z16; }
  float lsum[16];
#pragma unroll
  for (int j = 0; j < 16; ++j) lsum[j] = 0.f;

  for (int kt = 0; kt < 36; ++kt) {
    // issue V(kt) -> vlds (safe: barrier #3 of prev iter has passed)
#pragma unroll
    for (int i = 0; i < 6; ++i) {
      int cid = i * 4 + w, sc = cid * 64 + lane;
      int d = sc >> 3, pc = sc & 7;
      int gc = (pc ^ d) & 7;
      gll16(Vg + (size_t)d * NN + kt * 64 + gc * 8, &vlds[cid * 512]);
    }
    // wait only for K(kt) (all but the 6 newest V loads), no vm drain
    asm volatile("s_waitcnt vmcnt(6) lgkmcnt(0)\ns_barrier" ::: "memory");

    // ---- S = Q K^T : one 32x32 quadrant per wave, 2 independent chains ----
    f32x16 s0 = z16, s1 = z16;
    __builtin_amdgcn_s_setprio(1);
#pragma unroll
    for (int ks = 0; ks < 6; ++ks) {
      bf16x8 k0 = *(const bf16x8*)&klds[swzK(ch * 32 + l31, (2 * ks) * 16 + hi * 8)];
      bf16x8 k1 = *(const bf16x8*)&klds[swzK(ch * 32 + l31, (2 * ks + 1) * 16 + hi * 8)];
      s0 = __builtin_amdgcn_mfma_f32_32x32x16_bf16(qf[2 * ks], k0, s0, 0, 0, 0);
      s1 = __builtin_amdgcn_mfma_f32_32x32x16_bf16(qf[2 * ks + 1], k1, s1, 0, 0, 0);
    }
    __builtin_amdgcn_s_setprio(0);

    // ---- P: exp / relu^2, packed u32 store (lo=soft, hi=relu) ----
#pragma unroll
    for (int r = 0; r < 16; ++r) {
      float s = s0[r] + s1[r];
      float e = __expf(fminf(s, 60.f));
      float rl = (s > 0.f) ? s * s : 0.f;
      lsum[r] += e;
      int m = (r & 3) + 8 * (r >> 2) + 4 * hi;   // local q row 0..31
      int qL = qh * 32 + m;
      int c = ch * 32 + l31;                     // k col 0..63
      int chk = c >> 2;
      int phys = (chk & 8) | ((chk ^ (qL & 7)) & 7);
      pu[qL * 64 + phys * 4 + (c & 3)] =
          ((uint32_t)bf16bits(rl) << 16) | (uint32_t)bf16bits(e);
    }
    __syncthreads();   // #2: drains vmcnt(0) -> V(kt) visible; P visible

    // issue K(kt+1): klds free (all S reads done), flies under PV
    if (kt + 1 < 36) {
#pragma unroll
      for (int i = 0; i < 6; ++i) {
        int cid = i * 4 + w, sc = cid * 64 + lane;
        int row = sc / 24, pc = sc % 24;
        int gc = (pc & ~7) | ((pc ^ row) & 7);
        gll16(Kg + ((size_t)(kt + 1) * 64 + row) * CC + gc * 8, &klds[cid * 512]);
      }
    }

    // ---- O += P @ V (both branches share the V b-frag) ----
    __builtin_amdgcn_s_setprio(1);
#pragma unroll
    for (int ks4 = 0; ks4 < 4; ++ks4) {
      int qL = qh * 32 + l31;
      int c0 = 4 * ks4 + 2 * hi;
      int p0 = (c0 & 8) | ((c0 ^ (l31 & 7)) & 7);
      int c1 = c0 + 1;
      int p1 = (c1 & 8) | ((c1 ^ (l31 & 7)) & 7);
      uint32_t W[8];
      *(uint4*)&W[0] = *(const uint4*)&pu[qL * 64 + p0 * 4];
      *(uint4*)&W[4] = *(const uint4*)&pu[qL * 64 + p1 * 4];
      bf16x8 pfs, pfr;
      uint32_t* pw = (uint32_t*)&pfs;
      uint32_t* rw = (uint32_t*)&pfr;
#pragma unroll
      for (int p = 0; p < 4; ++p) {
        pw[p] = (W[2 * p] & 0xFFFFu) | (W[2 * p + 1] << 16);
        rw[p] = (W[2 * p] >> 16) | (W[2 * p + 1] & 0xFFFF0000u);
      }
#pragma unroll
      for (int dt = 0; dt < 3; ++dt) {
        bf16x8 vf = *(const bf16x8*)&vlds[swz64((ch * 3 + dt) * 32 + l31, ks4 * 16 + hi * 8)];
        os[dt] = __builtin_amdgcn_mfma_f32_32x32x16_bf16(pfs, vf, os[dt], 0, 0, 0);
        orl[dt] = __builtin_amdgcn_mfma_f32_32x32x16_bf16(pfr, vf, orl[dt], 0, 0, 0);
      }
    }
    __builtin_amdgcn_s_setprio(0);
    // #3: all LDS reads done; no vm drain (K(kt+1) stays in flight)
    asm volatile("s_waitcnt lgkmcnt(0)\ns_barrier" ::: "memory");
  }

  // ---- epilogue ----
  float e1 = __expf(w1p[0]), e2 = __expf(w2p[0]);
  float den = e1 + e2, c1f = e1 / den, c2f = e2 / den;
#pragma unroll
  for (int r = 0; r < 16; ++r) {
    float v = lsum[r];
    v += __shfl_xor(v, 1);
    v += __shfl_xor(v, 2);
    v += __shfl_xor(v, 4);
    v += __shfl_xor(v, 8);
    v += __shfl_xor(v, 16);
    lsum[r] = v;
  }
  if (l31 == 0) {
#pragma unroll
    for (int r = 0; r < 16; ++r) {
      int m = (r & 3) + 8 * (r >> 2) + 4 * hi;
      lbuf[(qh * 32 + m) * 2 + ch] = lsum[r];
    }
  }
  __syncthreads();
  float inv[16];
#pragma unroll
  for (int r = 0; r < 16; ++r) {
    int m = (r & 3) + 8 * (r >> 2) + 4 * hi;
    int q = qh * 32 + m;
    inv[r] = c1f / (lbuf[q * 2] + lbuf[q * 2 + 1]);
  }
  // blend + transpose into olds[d][q'] (q' = lane-XOR swizzle, conflict-free)
#pragma unroll
  for (int dt = 0; dt < 3; ++dt) {
    int d = (ch * 3 + dt) * 32 + l31;
#pragma unroll
    for (int r = 0; r < 16; ++r) {
      int m = (r & 3) + 8 * (r >> 2) + 4 * hi;
      int q = qh * 32 + m;
      olds[d * 64 + ((q & ~31) | ((q ^ d) & 31))] = os[dt][r] * inv[r] + c2f * orl[dt][r];
    }
  }
  __syncthreads();
  const float* xb = x + (size_t)b * CC * NN + qt * 64;
  float* ob = out + (size_t)b * CC * NN + qt * 64;
#pragma unroll
  for (int i = 0; i < 48; ++i) {
    int idx = i * 256 + t;
    int c = idx >> 6, nn = idx & 63;
    float v = olds[c * 64 + ((nn & ~31) | ((nn ^ c) & 31))];
    ob[(size_t)c * NN + nn] = v + xb[(size_t)c * NN + nn];
  }
}

// ---------------------------------------------------------------------------
extern "C" void kernel_launch(void* const* d_in, const int* in_sizes, int n_in,
                              void* d_out, int out_size, void* d_ws, size_t ws_size,
                              hipStream_t stream) {
  (void)in_sizes; (void)n_in; (void)out_size; (void)ws_size;
  const float* x   = (const float*)d_in[0];
  const float* lnw = (const float*)d_in[1];
  const float* lnb = (const float*)d_in[2];
  const float* Wq  = (const float*)d_in[3];
  const float* Wk  = (const float*)d_in[4];
  const float* Wv  = (const float*)d_in[5];
  const float* w1  = (const float*)d_in[6];
  const float* w2  = (const float*)d_in[7];
  float* out = (float*)d_out;

  u16* xn = (u16*)d_ws;
  size_t per = (size_t)NBATCH * NN * CC;
  u16* qb  = xn + per;
  u16* kb  = qb + per;
  u16* vtb = kb + per;

  ln_kernel<<<dim3(36, 16), 256, 0, stream>>>(x, lnw, lnb, xn);
  qkv_gemm<<<dim3(576, 3, 3), 256, 0, stream>>>(xn, Wq, Wk, Wv, qb, kb, vtb);
  attn_kernel<<<dim3(576), 256, 0, stream>>>(qb, kb, vtb, w1, w2, x, out);
}